// Round 1
// baseline (2570.885 us; speedup 1.0000x reference)
//
#include <hip/hip_runtime.h>
#include <hip/hip_bf16.h>

#define N_USERS   100000
#define N_ITEMS   50000
#define N_ENT     150000
#define N_EDGES   2000000
#define NNZ       1000000
#define CH        64

// ---------------- edge scatter: summed[head] += ent[tail], cnt[head]++ ----------------
__global__ void scatter_edges(const float* __restrict__ ent,
                              const int* __restrict__ head,
                              const int* __restrict__ tail,
                              float* __restrict__ summed,
                              float* __restrict__ cnt,
                              int do_cnt) {
    int idx = blockIdx.x * blockDim.x + threadIdx.x;   // < 128M, fits int
    int e = idx >> 6;
    int c = idx & 63;
    int h = head[e];
    int t = tail[e];
    atomicAdd(&summed[(size_t)h * CH + c], ent[(size_t)t * CH + c]);
    if (do_cnt && c == 0) atomicAdd(&cnt[h], 1.0f);
}

// ------------- entity finalize: agg = summed/max(cnt,1) (in place); -------------
// ------------- ent_next = l2norm(agg); out_ent += ent_next             -------------
__global__ void ent_finalize(float* __restrict__ summed,
                             const float* __restrict__ cnt,
                             float* __restrict__ ent_next,
                             float* __restrict__ out_ent) {
    int idx = blockIdx.x * blockDim.x + threadIdx.x;
    int row = idx >> 6;
    int c = idx & 63;
    if (row >= N_ENT) return;
    size_t o = (size_t)row * CH + c;
    float agg = summed[o] / fmaxf(cnt[row], 1.0f);
    summed[o] = agg;                       // un-normalized entity_agg (items source)
    float s = agg * agg;
    #pragma unroll
    for (int m = 32; m > 0; m >>= 1) s += __shfl_xor(s, m, 64);
    float nrm = fmaxf(sqrtf(s), 1e-12f);
    float v = agg / nrm;
    ent_next[o] = v;
    out_ent[o] += v;
}

// ------------- user_mean[u] += vals[n] * items[item[n]] -------------
__global__ void user_mean_k(const float* __restrict__ items,
                            const int* __restrict__ iu,
                            const int* __restrict__ ii,
                            const float* __restrict__ iv,
                            float* __restrict__ um) {
    int idx = blockIdx.x * blockDim.x + threadIdx.x;
    int n = idx >> 6;
    int c = idx & 63;
    int u = iu[n];
    int it = ii[n];
    float v = iv[n];
    atomicAdd(&um[(size_t)u * CH + c], v * items[(size_t)it * CH + c]);
}

// ------------- score[n] = ||items[it]-um[u]+eps||/T ; rowmax atomicMax -------------
__global__ void score_k(const float* __restrict__ items,
                        const float* __restrict__ um,
                        const int* __restrict__ iu,
                        const int* __restrict__ ii,
                        float* __restrict__ score,
                        unsigned int* __restrict__ rmax) {
    int idx = blockIdx.x * blockDim.x + threadIdx.x;
    int n = idx >> 6;
    int c = idx & 63;
    int u = iu[n];
    int it = ii[n];
    float d = items[(size_t)it * CH + c] - um[(size_t)u * CH + c] + 1e-6f;
    float s = d * d;
    #pragma unroll
    for (int m = 32; m > 0; m >>= 1) s += __shfl_xor(s, m, 64);
    if (c == 0) {
        float sc = sqrtf(s) * 5.0f;        // / TEMPERATURE (0.2)
        score[n] = sc;
        atomicMax(&rmax[u], __float_as_uint(sc));   // scores >= 0 -> uint order ok
    }
}

// ------------- e = exp(score - rowmax); denom[u] += e; score <- e -------------
__global__ void denom_k(float* __restrict__ score,
                        const unsigned int* __restrict__ rmax,
                        const int* __restrict__ iu,
                        float* __restrict__ denom) {
    int n = blockIdx.x * blockDim.x + threadIdx.x;
    if (n >= NNZ) return;
    int u = iu[n];
    float m = __uint_as_float(rmax[u]);
    float e = expf(score[n] - m);
    score[n] = e;                          // reuse buffer: holds e afterwards
    atomicAdd(&denom[u], e);
}

// ------------- user_agg[u] += (e/denom[u]) * items[it] -------------
__global__ void user_agg_k(const float* __restrict__ items,
                           const float* __restrict__ escore,
                           const float* __restrict__ denom,
                           const int* __restrict__ iu,
                           const int* __restrict__ ii,
                           float* __restrict__ uagg) {
    int idx = blockIdx.x * blockDim.x + threadIdx.x;
    int n = idx >> 6;
    int c = idx & 63;
    int u = iu[n];
    int it = ii[n];
    float soft = escore[n] / denom[u];
    atomicAdd(&uagg[(size_t)u * CH + c], soft * items[(size_t)it * CH + c]);
}

// ------------- out_user += l2norm(uagg) -------------
__global__ void user_fin(const float* __restrict__ uagg,
                         float* __restrict__ out_user) {
    int idx = blockIdx.x * blockDim.x + threadIdx.x;
    int row = idx >> 6;
    int c = idx & 63;
    if (row >= N_USERS) return;
    size_t o = (size_t)row * CH + c;
    float a = uagg[o];
    float s = a * a;
    #pragma unroll
    for (int m = 32; m > 0; m >>= 1) s += __shfl_xor(s, m, 64);
    float nrm = fmaxf(sqrtf(s), 1e-12f);
    out_user[o] += a / nrm;
}

extern "C" void kernel_launch(void* const* d_in, const int* in_sizes, int n_in,
                              void* d_out, int out_size, void* d_ws, size_t ws_size,
                              hipStream_t stream) {
    const float* user_emb   = (const float*)d_in[0];
    const float* entity_emb = (const float*)d_in[1];
    // d_in[2] = weight   (unused by reference)
    const int*   edge_index = (const int*)d_in[3];
    // d_in[4] = edge_type (unused by reference)
    const int*   iu = (const int*)d_in[5];
    const int*   ii = (const int*)d_in[6];
    const float* iv = (const float*)d_in[7];

    float* out_user = (float*)d_out;
    float* out_ent  = out_user + (size_t)N_USERS * CH;

    float* ws      = (float*)d_ws;
    float* ent_buf = ws;                               // 9.6M
    float* summed  = ent_buf + (size_t)N_ENT * CH;     // 9.6M
    float* um      = summed  + (size_t)N_ENT * CH;     // 6.4M
    float* uagg    = um      + (size_t)N_USERS * CH;   // 6.4M
    float* cnt     = uagg    + (size_t)N_USERS * CH;   // 150K
    float* rmax    = cnt     + N_ENT;                  // 100K
    float* denom   = rmax    + N_USERS;                // 100K
    float* score   = denom   + N_USERS;                // 1M

    const int* head = edge_index;
    const int* tail = edge_index + N_EDGES;

    // seed residuals
    hipMemcpyAsync(out_user, user_emb,   (size_t)N_USERS * CH * 4, hipMemcpyDeviceToDevice, stream);
    hipMemcpyAsync(out_ent,  entity_emb, (size_t)N_ENT   * CH * 4, hipMemcpyDeviceToDevice, stream);

    const float* ent_in = entity_emb;
    for (int hop = 0; hop < 2; ++hop) {
        hipMemsetAsync(summed, 0, (size_t)N_ENT * CH * 4, stream);
        if (hop == 0) hipMemsetAsync(cnt, 0, (size_t)N_ENT * 4, stream);
        hipMemsetAsync(um,    0, (size_t)N_USERS * CH * 4, stream);
        hipMemsetAsync(uagg,  0, (size_t)N_USERS * CH * 4, stream);
        hipMemsetAsync(rmax,  0, (size_t)N_USERS * 4, stream);
        hipMemsetAsync(denom, 0, (size_t)N_USERS * 4, stream);

        scatter_edges<<<(N_EDGES * CH) / 256, 256, 0, stream>>>(
            ent_in, head, tail, summed, cnt, hop == 0);

        ent_finalize<<<((size_t)N_ENT * CH) / 256, 256, 0, stream>>>(
            summed, cnt, ent_buf, out_ent);

        // items == summed[:N_ITEMS*CH] (un-normalized entity_agg)
        user_mean_k<<<(NNZ * CH) / 256, 256, 0, stream>>>(summed, iu, ii, iv, um);

        score_k<<<(NNZ * CH) / 256, 256, 0, stream>>>(
            summed, um, iu, ii, score, (unsigned int*)rmax);

        denom_k<<<(NNZ + 255) / 256, 256, 0, stream>>>(
            score, (const unsigned int*)rmax, iu, denom);

        user_agg_k<<<(NNZ * CH) / 256, 256, 0, stream>>>(
            summed, score, denom, iu, ii, uagg);

        user_fin<<<((size_t)N_USERS * CH) / 256, 256, 0, stream>>>(uagg, out_user);

        ent_in = ent_buf;
    }
}

// Round 3
// 1958.969 us; speedup vs baseline: 1.3124x; 1.3124x over previous
//
#include <hip/hip_runtime.h>
#include <hip/hip_bf16.h>

#define N_USERS   100000
#define N_ITEMS   50000
#define N_ENT     150000
#define N_EDGES   2000000
#define NNZ       1000000
#define CH        64

#define SCAN_BLOCK 256
#define ELEMS_PER_BLOCK 1024   // 4 per thread

// ---------------- CSR build: histogram of head ----------------
__global__ void hist_k(const int* __restrict__ head, unsigned int* __restrict__ cnt) {
    int e = blockIdx.x * blockDim.x + threadIdx.x;
    if (e >= N_EDGES) return;
    atomicAdd(&cnt[head[e]], 1u);
}

// ---------------- two-level exclusive scan ----------------
__global__ void scan1_k(const unsigned int* __restrict__ cnt,
                        unsigned int* __restrict__ excl,
                        unsigned int* __restrict__ partials, int n) {
    __shared__ unsigned int sdata[SCAN_BLOCK];
    int base = blockIdx.x * ELEMS_PER_BLOCK + threadIdx.x * 4;
    unsigned int v[4];
    unsigned int s = 0;
    #pragma unroll
    for (int k = 0; k < 4; ++k) {
        int i = base + k;
        v[k] = (i < n) ? cnt[i] : 0u;
        s += v[k];
    }
    sdata[threadIdx.x] = s;
    __syncthreads();
    for (int off = 1; off < SCAN_BLOCK; off <<= 1) {
        unsigned int t = 0;
        if ((int)threadIdx.x >= off) t = sdata[threadIdx.x - off];
        __syncthreads();
        if ((int)threadIdx.x >= off) sdata[threadIdx.x] += t;
        __syncthreads();
    }
    unsigned int run = sdata[threadIdx.x] - s;   // exclusive prefix of this thread
    #pragma unroll
    for (int k = 0; k < 4; ++k) {
        int i = base + k;
        if (i < n) excl[i] = run;
        run += v[k];
    }
    if (threadIdx.x == SCAN_BLOCK - 1) partials[blockIdx.x] = sdata[SCAN_BLOCK - 1];
}

__global__ void scan2_k(unsigned int* __restrict__ partials, int n2) {
    __shared__ unsigned int sdata[SCAN_BLOCK];
    unsigned int v = (threadIdx.x < (unsigned)n2) ? partials[threadIdx.x] : 0u;
    sdata[threadIdx.x] = v;
    __syncthreads();
    for (int off = 1; off < SCAN_BLOCK; off <<= 1) {
        unsigned int t = 0;
        if ((int)threadIdx.x >= off) t = sdata[threadIdx.x - off];
        __syncthreads();
        if ((int)threadIdx.x >= off) sdata[threadIdx.x] += t;
        __syncthreads();
    }
    if (threadIdx.x < (unsigned)n2) partials[threadIdx.x] = sdata[threadIdx.x] - v; // exclusive
}

__global__ void addoff_k(unsigned int* __restrict__ excl,
                         const unsigned int* __restrict__ partials,
                         int n, unsigned int total) {
    int base = blockIdx.x * ELEMS_PER_BLOCK + threadIdx.x * 4;
    unsigned int p = partials[blockIdx.x];
    #pragma unroll
    for (int k = 0; k < 4; ++k) {
        int i = base + k;
        if (i < n) excl[i] += p;
    }
    if (blockIdx.x == 0 && threadIdx.x == 0) excl[n] = total;
}

// ---------------- bucket scatter: col[pos] = tail[e] ----------------
__global__ void scatter_ids_k(const int* __restrict__ head,
                              const int* __restrict__ tail,
                              unsigned int* __restrict__ cursor,
                              int* __restrict__ col) {
    int e = blockIdx.x * blockDim.x + threadIdx.x;
    if (e >= N_EDGES) return;
    unsigned int pos = atomicAdd(&cursor[head[e]], 1u);
    col[pos] = tail[e];
}

// ------------- CSR gather: one wave per entity row -------------
// summed[row] = (sum_{j} ent[col[j]]) / max(deg,1)
// NOTE: reads `ent` (previous hop's normalized buffer) and writes ONLY
// `summed` — normalize/residual is a separate kernel to avoid the
// read-write hazard on ent_buf in hop 1 (Round 2 bug).
__global__ void gather_edges(const float* __restrict__ ent,
                             const unsigned int* __restrict__ row_start,
                             const int* __restrict__ col,
                             float* __restrict__ summed) {
    int wave = (blockIdx.x * blockDim.x + threadIdx.x) >> 6;
    int lane = threadIdx.x & 63;
    if (wave >= N_ENT) return;
    unsigned int s0 = row_start[wave];
    unsigned int s1 = row_start[wave + 1];
    float acc = 0.0f;
    unsigned int j = s0;
    for (; j + 4 <= s1; j += 4) {
        int t0 = col[j], t1 = col[j + 1], t2 = col[j + 2], t3 = col[j + 3];
        float a0 = ent[(size_t)t0 * CH + lane];
        float a1 = ent[(size_t)t1 * CH + lane];
        float a2 = ent[(size_t)t2 * CH + lane];
        float a3 = ent[(size_t)t3 * CH + lane];
        acc += a0 + a1 + a2 + a3;
    }
    for (; j < s1; ++j) acc += ent[(size_t)col[j] * CH + lane];
    float deg = (float)(s1 - s0);
    summed[(size_t)wave * CH + lane] = acc / fmaxf(deg, 1.0f);
}

// ------------- ent_next = l2norm(summed); out_ent += ent_next -------------
__global__ void ent_finalize(const float* __restrict__ summed,
                             float* __restrict__ ent_next,
                             float* __restrict__ out_ent) {
    int idx = blockIdx.x * blockDim.x + threadIdx.x;
    int row = idx >> 6;
    int c = idx & 63;
    if (row >= N_ENT) return;
    size_t o = (size_t)row * CH + c;
    float agg = summed[o];
    float s = agg * agg;
    #pragma unroll
    for (int m = 32; m > 0; m >>= 1) s += __shfl_xor(s, m, 64);
    float v = agg / fmaxf(sqrtf(s), 1e-12f);
    ent_next[o] = v;
    out_ent[o] += v;
}

// ------------- user_mean[u] += vals[n] * items[item[n]] -------------
__global__ void user_mean_k(const float* __restrict__ items,
                            const int* __restrict__ iu,
                            const int* __restrict__ ii,
                            const float* __restrict__ iv,
                            float* __restrict__ um) {
    int idx = blockIdx.x * blockDim.x + threadIdx.x;
    int n = idx >> 6;
    int c = idx & 63;
    int u = iu[n];
    int it = ii[n];
    float v = iv[n];
    atomicAdd(&um[(size_t)u * CH + c], v * items[(size_t)it * CH + c]);
}

// ------------- score[n] = ||items[it]-um[u]+eps||/T ; rowmax atomicMax -------------
__global__ void score_k(const float* __restrict__ items,
                        const float* __restrict__ um,
                        const int* __restrict__ iu,
                        const int* __restrict__ ii,
                        float* __restrict__ score,
                        unsigned int* __restrict__ rmax) {
    int idx = blockIdx.x * blockDim.x + threadIdx.x;
    int n = idx >> 6;
    int c = idx & 63;
    int u = iu[n];
    int it = ii[n];
    float d = items[(size_t)it * CH + c] - um[(size_t)u * CH + c] + 1e-6f;
    float s = d * d;
    #pragma unroll
    for (int m = 32; m > 0; m >>= 1) s += __shfl_xor(s, m, 64);
    if (c == 0) {
        float sc = sqrtf(s) * 5.0f;        // / TEMPERATURE (0.2)
        score[n] = sc;
        atomicMax(&rmax[u], __float_as_uint(sc));   // scores >= 0 -> uint order ok
    }
}

// ------------- e = exp(score - rowmax); denom[u] += e; score <- e -------------
__global__ void denom_k(float* __restrict__ score,
                        const unsigned int* __restrict__ rmax,
                        const int* __restrict__ iu,
                        float* __restrict__ denom) {
    int n = blockIdx.x * blockDim.x + threadIdx.x;
    if (n >= NNZ) return;
    int u = iu[n];
    float m = __uint_as_float(rmax[u]);
    float e = expf(score[n] - m);
    score[n] = e;                          // reuse buffer: holds e afterwards
    atomicAdd(&denom[u], e);
}

// ------------- user_agg[u] += (e/denom[u]) * items[it] -------------
__global__ void user_agg_k(const float* __restrict__ items,
                           const float* __restrict__ escore,
                           const float* __restrict__ denom,
                           const int* __restrict__ iu,
                           const int* __restrict__ ii,
                           float* __restrict__ uagg) {
    int idx = blockIdx.x * blockDim.x + threadIdx.x;
    int n = idx >> 6;
    int c = idx & 63;
    int u = iu[n];
    int it = ii[n];
    float soft = escore[n] / denom[u];
    atomicAdd(&uagg[(size_t)u * CH + c], soft * items[(size_t)it * CH + c]);
}

// ------------- out_user += l2norm(uagg) -------------
__global__ void user_fin(const float* __restrict__ uagg,
                         float* __restrict__ out_user) {
    int idx = blockIdx.x * blockDim.x + threadIdx.x;
    int row = idx >> 6;
    int c = idx & 63;
    if (row >= N_USERS) return;
    size_t o = (size_t)row * CH + c;
    float a = uagg[o];
    float s = a * a;
    #pragma unroll
    for (int m = 32; m > 0; m >>= 1) s += __shfl_xor(s, m, 64);
    float nrm = fmaxf(sqrtf(s), 1e-12f);
    out_user[o] += a / nrm;
}

extern "C" void kernel_launch(void* const* d_in, const int* in_sizes, int n_in,
                              void* d_out, int out_size, void* d_ws, size_t ws_size,
                              hipStream_t stream) {
    const float* user_emb   = (const float*)d_in[0];
    const float* entity_emb = (const float*)d_in[1];
    // d_in[2] = weight   (unused by reference)
    const int*   edge_index = (const int*)d_in[3];
    // d_in[4] = edge_type (unused by reference)
    const int*   iu = (const int*)d_in[5];
    const int*   ii = (const int*)d_in[6];
    const float* iv = (const float*)d_in[7];

    float* out_user = (float*)d_out;
    float* out_ent  = out_user + (size_t)N_USERS * CH;

    float* ws      = (float*)d_ws;
    float* ent_buf = ws;                               // 9.6M
    float* summed  = ent_buf + (size_t)N_ENT * CH;     // 9.6M
    float* um      = summed  + (size_t)N_ENT * CH;     // 6.4M
    float* uagg    = um      + (size_t)N_USERS * CH;   // 6.4M
    float* rmax    = uagg    + (size_t)N_USERS * CH;   // 100K
    float* denom   = rmax    + N_USERS;                // 100K
    float* score   = denom   + N_USERS;                // 1M
    // u32/int CSR region
    unsigned int* cnt_u    = (unsigned int*)(score + NNZ);        // 150K
    unsigned int* row_start= cnt_u + N_ENT;                       // 150001
    unsigned int* cursor   = row_start + (N_ENT + 1);             // 150001
    unsigned int* partials = cursor + (N_ENT + 1);                // 256
    int*          col      = (int*)(partials + 256);              // 2M

    const int* head = edge_index;
    const int* tail = edge_index + N_EDGES;

    const int nScanBlocks = (N_ENT + ELEMS_PER_BLOCK - 1) / ELEMS_PER_BLOCK;  // 147

    // ---- CSR build (edge structure constant across hops) ----
    hipMemsetAsync(cnt_u, 0, (size_t)N_ENT * 4, stream);
    hist_k<<<(N_EDGES + 255) / 256, 256, 0, stream>>>(head, cnt_u);
    scan1_k<<<nScanBlocks, SCAN_BLOCK, 0, stream>>>(cnt_u, row_start, partials, N_ENT);
    scan2_k<<<1, SCAN_BLOCK, 0, stream>>>(partials, nScanBlocks);
    addoff_k<<<nScanBlocks, SCAN_BLOCK, 0, stream>>>(row_start, partials, N_ENT, N_EDGES);
    hipMemcpyAsync(cursor, row_start, (size_t)(N_ENT + 1) * 4, hipMemcpyDeviceToDevice, stream);
    scatter_ids_k<<<(N_EDGES + 255) / 256, 256, 0, stream>>>(head, tail, cursor, col);

    // seed residuals
    hipMemcpyAsync(out_user, user_emb,   (size_t)N_USERS * CH * 4, hipMemcpyDeviceToDevice, stream);
    hipMemcpyAsync(out_ent,  entity_emb, (size_t)N_ENT   * CH * 4, hipMemcpyDeviceToDevice, stream);

    const float* ent_in = entity_emb;
    for (int hop = 0; hop < 2; ++hop) {
        hipMemsetAsync(um,    0, (size_t)N_USERS * CH * 4, stream);
        hipMemsetAsync(uagg,  0, (size_t)N_USERS * CH * 4, stream);
        hipMemsetAsync(rmax,  0, (size_t)N_USERS * 4, stream);
        hipMemsetAsync(denom, 0, (size_t)N_USERS * 4, stream);

        gather_edges<<<((size_t)N_ENT * CH + 255) / 256, 256, 0, stream>>>(
            ent_in, row_start, col, summed);

        ent_finalize<<<((size_t)N_ENT * CH + 255) / 256, 256, 0, stream>>>(
            summed, ent_buf, out_ent);

        // items == summed[:N_ITEMS*CH] (un-normalized entity_agg)
        user_mean_k<<<(NNZ * CH) / 256, 256, 0, stream>>>(summed, iu, ii, iv, um);

        score_k<<<(NNZ * CH) / 256, 256, 0, stream>>>(
            summed, um, iu, ii, score, (unsigned int*)rmax);

        denom_k<<<(NNZ + 255) / 256, 256, 0, stream>>>(
            score, (const unsigned int*)rmax, iu, denom);

        user_agg_k<<<(NNZ * CH) / 256, 256, 0, stream>>>(
            summed, score, denom, iu, ii, uagg);

        user_fin<<<((size_t)N_USERS * CH) / 256, 256, 0, stream>>>(uagg, out_user);

        ent_in = ent_buf;
    }
}

// Round 4
// 1036.204 us; speedup vs baseline: 2.4811x; 1.8905x over previous
//
#include <hip/hip_runtime.h>
#include <hip/hip_bf16.h>

#define N_USERS   100000
#define N_ITEMS   50000
#define N_ENT     150000
#define N_EDGES   2000000
#define NNZ       1000000
#define CH        64

#define SCAN_BLOCK 256
#define ELEMS_PER_BLOCK 1024   // 4 per thread

// ---------------- generic histogram ----------------
__global__ void hist_k(const int* __restrict__ key, unsigned int* __restrict__ cnt, int n) {
    int e = blockIdx.x * blockDim.x + threadIdx.x;
    if (e >= n) return;
    atomicAdd(&cnt[key[e]], 1u);
}

// ---------------- two-level exclusive scan ----------------
__global__ void scan1_k(const unsigned int* __restrict__ cnt,
                        unsigned int* __restrict__ excl,
                        unsigned int* __restrict__ partials, int n) {
    __shared__ unsigned int sdata[SCAN_BLOCK];
    int base = blockIdx.x * ELEMS_PER_BLOCK + threadIdx.x * 4;
    unsigned int v[4];
    unsigned int s = 0;
    #pragma unroll
    for (int k = 0; k < 4; ++k) {
        int i = base + k;
        v[k] = (i < n) ? cnt[i] : 0u;
        s += v[k];
    }
    sdata[threadIdx.x] = s;
    __syncthreads();
    for (int off = 1; off < SCAN_BLOCK; off <<= 1) {
        unsigned int t = 0;
        if ((int)threadIdx.x >= off) t = sdata[threadIdx.x - off];
        __syncthreads();
        if ((int)threadIdx.x >= off) sdata[threadIdx.x] += t;
        __syncthreads();
    }
    unsigned int run = sdata[threadIdx.x] - s;   // exclusive prefix of this thread
    #pragma unroll
    for (int k = 0; k < 4; ++k) {
        int i = base + k;
        if (i < n) excl[i] = run;
        run += v[k];
    }
    if (threadIdx.x == SCAN_BLOCK - 1) partials[blockIdx.x] = sdata[SCAN_BLOCK - 1];
}

__global__ void scan2_k(unsigned int* __restrict__ partials, int n2) {
    __shared__ unsigned int sdata[SCAN_BLOCK];
    unsigned int v = (threadIdx.x < (unsigned)n2) ? partials[threadIdx.x] : 0u;
    sdata[threadIdx.x] = v;
    __syncthreads();
    for (int off = 1; off < SCAN_BLOCK; off <<= 1) {
        unsigned int t = 0;
        if ((int)threadIdx.x >= off) t = sdata[threadIdx.x - off];
        __syncthreads();
        if ((int)threadIdx.x >= off) sdata[threadIdx.x] += t;
        __syncthreads();
    }
    if (threadIdx.x < (unsigned)n2) partials[threadIdx.x] = sdata[threadIdx.x] - v; // exclusive
}

__global__ void addoff_k(unsigned int* __restrict__ excl,
                         const unsigned int* __restrict__ partials,
                         int n, unsigned int total) {
    int base = blockIdx.x * ELEMS_PER_BLOCK + threadIdx.x * 4;
    unsigned int p = partials[blockIdx.x];
    #pragma unroll
    for (int k = 0; k < 4; ++k) {
        int i = base + k;
        if (i < n) excl[i] += p;
    }
    if (blockIdx.x == 0 && threadIdx.x == 0) excl[n] = total;
}

// ---------------- bucket scatter: edge CSR (col[pos] = tail[e]) ----------------
__global__ void scatter_ids_k(const int* __restrict__ head,
                              const int* __restrict__ tail,
                              unsigned int* __restrict__ cursor,
                              int* __restrict__ col) {
    int e = blockIdx.x * blockDim.x + threadIdx.x;
    if (e >= N_EDGES) return;
    unsigned int pos = atomicAdd(&cursor[head[e]], 1u);
    col[pos] = tail[e];
}

// ---------------- bucket scatter: user CSR ((item,val) pairs) ----------------
__global__ void scatter_pairs_k(const int* __restrict__ iu,
                                const int* __restrict__ ii,
                                const float* __restrict__ iv,
                                unsigned int* __restrict__ cursor,
                                int* __restrict__ ci,
                                float* __restrict__ cv) {
    int n = blockIdx.x * blockDim.x + threadIdx.x;
    if (n >= NNZ) return;
    unsigned int pos = atomicAdd(&cursor[iu[n]], 1u);
    ci[pos] = ii[n];
    cv[pos] = iv[n];
}

// ------------- CSR gather: one wave per entity row -------------
// summed[row] = (sum_{j} ent[col[j]]) / max(deg,1)
// Reads `ent`, writes ONLY `summed` (normalize split out to avoid the
// Round-2 read/write hazard on ent_buf in hop 1).
__global__ void gather_edges(const float* __restrict__ ent,
                             const unsigned int* __restrict__ row_start,
                             const int* __restrict__ col,
                             float* __restrict__ summed) {
    int wave = (blockIdx.x * blockDim.x + threadIdx.x) >> 6;
    int lane = threadIdx.x & 63;
    if (wave >= N_ENT) return;
    unsigned int s0 = row_start[wave];
    unsigned int s1 = row_start[wave + 1];
    float acc = 0.0f;
    unsigned int j = s0;
    for (; j + 4 <= s1; j += 4) {
        int t0 = col[j], t1 = col[j + 1], t2 = col[j + 2], t3 = col[j + 3];
        float a0 = ent[(size_t)t0 * CH + lane];
        float a1 = ent[(size_t)t1 * CH + lane];
        float a2 = ent[(size_t)t2 * CH + lane];
        float a3 = ent[(size_t)t3 * CH + lane];
        acc += a0 + a1 + a2 + a3;
    }
    for (; j < s1; ++j) acc += ent[(size_t)col[j] * CH + lane];
    float deg = (float)(s1 - s0);
    summed[(size_t)wave * CH + lane] = acc / fmaxf(deg, 1.0f);
}

// ------------- ent_next = l2norm(summed); out_ent += ent_next -------------
__global__ void ent_finalize(const float* __restrict__ summed,
                             float* __restrict__ ent_next,
                             float* __restrict__ out_ent) {
    int idx = blockIdx.x * blockDim.x + threadIdx.x;
    int row = idx >> 6;
    int c = idx & 63;
    if (row >= N_ENT) return;
    size_t o = (size_t)row * CH + c;
    float agg = summed[o];
    float s = agg * agg;
    #pragma unroll
    for (int m = 32; m > 0; m >>= 1) s += __shfl_xor(s, m, 64);
    float v = agg / fmaxf(sqrtf(s), 1e-12f);
    ent_next[o] = v;
    out_ent[o] += v;
}

// ------------- fused user pipeline: one wave per user, lane = channel -------------
// pass 1: um = sum_j cv[j] * items[ci[j]]          (register)
// pass 2: online softmax over scores ||g - um + eps||/T, accumulating
//         acc = sum_j softmax_j * g_j  (rescaled running form)
// epilogue: out_user += l2norm(acc / l)
__global__ void fused_user(const float* __restrict__ items,
                           const unsigned int* __restrict__ u_row_start,
                           const int* __restrict__ ci,
                           const float* __restrict__ cv,
                           float* __restrict__ out_user) {
    int wave = (blockIdx.x * blockDim.x + threadIdx.x) >> 6;
    int lane = threadIdx.x & 63;
    if (wave >= N_USERS) return;
    unsigned int s0 = u_row_start[wave];
    unsigned int s1 = u_row_start[wave + 1];

    // ---- pass 1: weighted sum (reference's "user_mean") ----
    float um = 0.0f;
    unsigned int j = s0;
    for (; j + 2 <= s1; j += 2) {
        int i0 = ci[j], i1 = ci[j + 1];
        float v0 = cv[j], v1 = cv[j + 1];
        um += v0 * items[(size_t)i0 * CH + lane];
        um += v1 * items[(size_t)i1 * CH + lane];
    }
    for (; j < s1; ++j) um += cv[j] * items[(size_t)ci[j] * CH + lane];

    // ---- pass 2: online softmax + weighted accumulate ----
    float m = -1e30f, l = 0.0f, acc = 0.0f;
    for (j = s0; j < s1; ++j) {
        float g = items[(size_t)ci[j] * CH + lane];
        float d = g - um + 1e-6f;
        float sq = d * d;
        #pragma unroll
        for (int mm = 32; mm > 0; mm >>= 1) sq += __shfl_xor(sq, mm, 64);
        float sc = sqrtf(sq) * 5.0f;          // / TEMPERATURE (0.2)
        float mn = fmaxf(m, sc);
        float scale = expf(m - mn);           // first iter: exp(-inf) -> 0
        float e = expf(sc - mn);
        l = l * scale + e;
        acc = acc * scale + e * g;
        m = mn;
    }

    // ---- epilogue: user_agg = acc/l; out_user += l2norm(user_agg) ----
    float ua = (l > 0.0f) ? (acc / l) : 0.0f; // empty user -> 0 (matches JAX 0/eps)
    float sq = ua * ua;
    #pragma unroll
    for (int mm = 32; mm > 0; mm >>= 1) sq += __shfl_xor(sq, mm, 64);
    float v = ua / fmaxf(sqrtf(sq), 1e-12f);
    out_user[(size_t)wave * CH + lane] += v;
}

extern "C" void kernel_launch(void* const* d_in, const int* in_sizes, int n_in,
                              void* d_out, int out_size, void* d_ws, size_t ws_size,
                              hipStream_t stream) {
    const float* user_emb   = (const float*)d_in[0];
    const float* entity_emb = (const float*)d_in[1];
    // d_in[2] = weight   (unused by reference)
    const int*   edge_index = (const int*)d_in[3];
    // d_in[4] = edge_type (unused by reference)
    const int*   iu = (const int*)d_in[5];
    const int*   ii = (const int*)d_in[6];
    const float* iv = (const float*)d_in[7];

    float* out_user = (float*)d_out;
    float* out_ent  = out_user + (size_t)N_USERS * CH;

    float* ws      = (float*)d_ws;
    float* ent_buf = ws;                               // N_ENT*CH
    float* summed  = ent_buf + (size_t)N_ENT * CH;     // N_ENT*CH
    // entity CSR
    unsigned int* cnt_u     = (unsigned int*)(summed + (size_t)N_ENT * CH); // N_ENT
    unsigned int* row_start = cnt_u + N_ENT;                                // N_ENT+1
    unsigned int* cursor    = row_start + (N_ENT + 1);                      // N_ENT+1
    unsigned int* partials  = cursor + (N_ENT + 1);                         // 256
    int*          col       = (int*)(partials + 256);                       // N_EDGES
    // user CSR
    unsigned int* ucnt        = (unsigned int*)(col + N_EDGES);             // N_USERS
    unsigned int* u_row_start = ucnt + N_USERS;                             // N_USERS+1
    unsigned int* ucursor     = u_row_start + (N_USERS + 1);                // N_USERS+1
    unsigned int* upartials   = ucursor + (N_USERS + 1);                    // 256
    int*          ci          = (int*)(upartials + 256);                    // NNZ
    float*        cv          = (float*)(ci + NNZ);                         // NNZ

    const int* head = edge_index;
    const int* tail = edge_index + N_EDGES;

    const int nScanE = (N_ENT   + ELEMS_PER_BLOCK - 1) / ELEMS_PER_BLOCK;   // 147
    const int nScanU = (N_USERS + ELEMS_PER_BLOCK - 1) / ELEMS_PER_BLOCK;   // 98

    // ---- entity CSR build (structure constant across hops) ----
    hipMemsetAsync(cnt_u, 0, (size_t)N_ENT * 4, stream);
    hist_k<<<(N_EDGES + 255) / 256, 256, 0, stream>>>(head, cnt_u, N_EDGES);
    scan1_k<<<nScanE, SCAN_BLOCK, 0, stream>>>(cnt_u, row_start, partials, N_ENT);
    scan2_k<<<1, SCAN_BLOCK, 0, stream>>>(partials, nScanE);
    addoff_k<<<nScanE, SCAN_BLOCK, 0, stream>>>(row_start, partials, N_ENT, N_EDGES);
    hipMemcpyAsync(cursor, row_start, (size_t)(N_ENT + 1) * 4, hipMemcpyDeviceToDevice, stream);
    scatter_ids_k<<<(N_EDGES + 255) / 256, 256, 0, stream>>>(head, tail, cursor, col);

    // ---- user CSR build ----
    hipMemsetAsync(ucnt, 0, (size_t)N_USERS * 4, stream);
    hist_k<<<(NNZ + 255) / 256, 256, 0, stream>>>(iu, ucnt, NNZ);
    scan1_k<<<nScanU, SCAN_BLOCK, 0, stream>>>(ucnt, u_row_start, upartials, N_USERS);
    scan2_k<<<1, SCAN_BLOCK, 0, stream>>>(upartials, nScanU);
    addoff_k<<<nScanU, SCAN_BLOCK, 0, stream>>>(u_row_start, upartials, N_USERS, NNZ);
    hipMemcpyAsync(ucursor, u_row_start, (size_t)(N_USERS + 1) * 4, hipMemcpyDeviceToDevice, stream);
    scatter_pairs_k<<<(NNZ + 255) / 256, 256, 0, stream>>>(iu, ii, iv, ucursor, ci, cv);

    // seed residuals
    hipMemcpyAsync(out_user, user_emb,   (size_t)N_USERS * CH * 4, hipMemcpyDeviceToDevice, stream);
    hipMemcpyAsync(out_ent,  entity_emb, (size_t)N_ENT   * CH * 4, hipMemcpyDeviceToDevice, stream);

    const float* ent_in = entity_emb;
    for (int hop = 0; hop < 2; ++hop) {
        gather_edges<<<((size_t)N_ENT * CH + 255) / 256, 256, 0, stream>>>(
            ent_in, row_start, col, summed);

        ent_finalize<<<((size_t)N_ENT * CH + 255) / 256, 256, 0, stream>>>(
            summed, ent_buf, out_ent);

        // items == summed[:N_ITEMS*CH] (un-normalized entity_agg)
        fused_user<<<((size_t)N_USERS * CH + 255) / 256, 256, 0, stream>>>(
            summed, u_row_start, ci, cv, out_user);

        ent_in = ent_buf;
    }
}

// Round 5
// 873.092 us; speedup vs baseline: 2.9446x; 1.1868x over previous
//
#include <hip/hip_runtime.h>
#include <hip/hip_bf16.h>

#define N_USERS   100000
#define N_ITEMS   50000
#define N_ENT     150000
#define N_EDGES   2000000
#define NNZ       1000000
#define CH        64

#define SCAN_BLOCK 256
#define ELEMS_PER_BLOCK 1024   // 4 per thread

// ---------------- generic histogram ----------------
__global__ void hist_k(const int* __restrict__ key, unsigned int* __restrict__ cnt, int n) {
    int e = blockIdx.x * blockDim.x + threadIdx.x;
    if (e >= n) return;
    atomicAdd(&cnt[key[e]], 1u);
}

// ---------------- two-level exclusive scan ----------------
__global__ void scan1_k(const unsigned int* __restrict__ cnt,
                        unsigned int* __restrict__ excl,
                        unsigned int* __restrict__ partials, int n) {
    __shared__ unsigned int sdata[SCAN_BLOCK];
    int base = blockIdx.x * ELEMS_PER_BLOCK + threadIdx.x * 4;
    unsigned int v[4];
    unsigned int s = 0;
    #pragma unroll
    for (int k = 0; k < 4; ++k) {
        int i = base + k;
        v[k] = (i < n) ? cnt[i] : 0u;
        s += v[k];
    }
    sdata[threadIdx.x] = s;
    __syncthreads();
    for (int off = 1; off < SCAN_BLOCK; off <<= 1) {
        unsigned int t = 0;
        if ((int)threadIdx.x >= off) t = sdata[threadIdx.x - off];
        __syncthreads();
        if ((int)threadIdx.x >= off) sdata[threadIdx.x] += t;
        __syncthreads();
    }
    unsigned int run = sdata[threadIdx.x] - s;   // exclusive prefix of this thread
    #pragma unroll
    for (int k = 0; k < 4; ++k) {
        int i = base + k;
        if (i < n) excl[i] = run;
        run += v[k];
    }
    if (threadIdx.x == SCAN_BLOCK - 1) partials[blockIdx.x] = sdata[SCAN_BLOCK - 1];
}

__global__ void scan2_k(unsigned int* __restrict__ partials, int n2) {
    __shared__ unsigned int sdata[SCAN_BLOCK];
    unsigned int v = (threadIdx.x < (unsigned)n2) ? partials[threadIdx.x] : 0u;
    sdata[threadIdx.x] = v;
    __syncthreads();
    for (int off = 1; off < SCAN_BLOCK; off <<= 1) {
        unsigned int t = 0;
        if ((int)threadIdx.x >= off) t = sdata[threadIdx.x - off];
        __syncthreads();
        if ((int)threadIdx.x >= off) sdata[threadIdx.x] += t;
        __syncthreads();
    }
    if (threadIdx.x < (unsigned)n2) partials[threadIdx.x] = sdata[threadIdx.x] - v; // exclusive
}

__global__ void addoff_k(unsigned int* __restrict__ excl,
                         const unsigned int* __restrict__ partials,
                         int n, unsigned int total) {
    int base = blockIdx.x * ELEMS_PER_BLOCK + threadIdx.x * 4;
    unsigned int p = partials[blockIdx.x];
    #pragma unroll
    for (int k = 0; k < 4; ++k) {
        int i = base + k;
        if (i < n) excl[i] += p;
    }
    if (blockIdx.x == 0 && threadIdx.x == 0) excl[n] = total;
}

// ---------------- bucket scatter: edge CSR (col[pos] = tail[e]) ----------------
__global__ void scatter_ids_k(const int* __restrict__ head,
                              const int* __restrict__ tail,
                              unsigned int* __restrict__ cursor,
                              int* __restrict__ col) {
    int e = blockIdx.x * blockDim.x + threadIdx.x;
    if (e >= N_EDGES) return;
    unsigned int pos = atomicAdd(&cursor[head[e]], 1u);
    col[pos] = tail[e];
}

// ---------------- bucket scatter: user CSR ((item,val) pairs) ----------------
__global__ void scatter_pairs_k(const int* __restrict__ iu,
                                const int* __restrict__ ii,
                                const float* __restrict__ iv,
                                unsigned int* __restrict__ cursor,
                                int* __restrict__ ci,
                                float* __restrict__ cv) {
    int n = blockIdx.x * blockDim.x + threadIdx.x;
    if (n >= NNZ) return;
    unsigned int pos = atomicAdd(&cursor[iu[n]], 1u);
    ci[pos] = ii[n];
    cv[pos] = iv[n];
}

// ------------- CSR gather: one wave per entity row, 4x16-lane groups -------------
// Group g handles neighbors s0+g, s0+g+4, ...; lane t (0..15) holds channels
// 4t..4t+3 as float4. Merge partial sums across groups at the end.
__global__ void gather_edges(const float* __restrict__ ent,
                             const unsigned int* __restrict__ row_start,
                             const int* __restrict__ col,
                             float* __restrict__ summed) {
    int wave = (blockIdx.x * blockDim.x + threadIdx.x) >> 6;
    int lane = threadIdx.x & 63;
    if (wave >= N_ENT) return;
    int grp = lane >> 4;
    int t   = lane & 15;
    unsigned int s0 = row_start[wave];
    unsigned int s1 = row_start[wave + 1];
    const float4* entv = (const float4*)ent;   // row stride = 16 float4

    float4 acc = make_float4(0.f, 0.f, 0.f, 0.f);
    unsigned int j = s0 + grp;
    for (; j + 4 < s1; j += 8) {               // 2 neighbors per group per iter
        float4 a = entv[(size_t)col[j]     * 16 + t];
        float4 b = entv[(size_t)col[j + 4] * 16 + t];
        acc.x += a.x + b.x; acc.y += a.y + b.y;
        acc.z += a.z + b.z; acc.w += a.w + b.w;
    }
    if (j < s1) {
        float4 a = entv[(size_t)col[j] * 16 + t];
        acc.x += a.x; acc.y += a.y; acc.z += a.z; acc.w += a.w;
    }
    // merge across the 4 groups
    #pragma unroll
    for (int m = 16; m <= 32; m <<= 1) {
        acc.x += __shfl_xor(acc.x, m, 64);
        acc.y += __shfl_xor(acc.y, m, 64);
        acc.z += __shfl_xor(acc.z, m, 64);
        acc.w += __shfl_xor(acc.w, m, 64);
    }
    if (grp == 0) {
        float inv = 1.0f / fmaxf((float)(s1 - s0), 1.0f);
        float4 r = make_float4(acc.x * inv, acc.y * inv, acc.z * inv, acc.w * inv);
        ((float4*)summed)[(size_t)wave * 16 + t] = r;
    }
}

// ------------- ent_next = l2norm(summed); out_ent += ent_next -------------
// one thread per float4; 16 consecutive lanes = one row
__global__ void ent_finalize(const float* __restrict__ summed,
                             float* __restrict__ ent_next,
                             float* __restrict__ out_ent) {
    int idx = blockIdx.x * blockDim.x + threadIdx.x;
    int row = idx >> 4;
    int t = idx & 15;
    if (row >= N_ENT) return;
    size_t o = (size_t)row * 16 + t;
    float4 a = ((const float4*)summed)[o];
    float sq = a.x * a.x + a.y * a.y + a.z * a.z + a.w * a.w;
    #pragma unroll
    for (int m = 1; m <= 8; m <<= 1) sq += __shfl_xor(sq, m, 64);
    float inv = 1.0f / fmaxf(sqrtf(sq), 1e-12f);
    float4 v = make_float4(a.x * inv, a.y * inv, a.z * inv, a.w * inv);
    ((float4*)ent_next)[o] = v;
    float4 c = ((float4*)out_ent)[o];
    c.x += v.x; c.y += v.y; c.z += v.z; c.w += v.w;
    ((float4*)out_ent)[o] = c;
}

// ------------- fused user pipeline: one wave per user, 4x16-lane groups -------------
// pass 1: um = sum_j cv[j]*items[ci[j]]  (per-group partial, merged via shfl)
// pass 2: per-group online softmax over scores ||g-um+eps||/T with rescaled
//         accumulator; groups merged associatively: w_g = exp(m_g - M).
// epilogue: out_user += l2norm(acc/l)
__global__ void fused_user(const float* __restrict__ items,
                           const unsigned int* __restrict__ u_row_start,
                           const int* __restrict__ ci,
                           const float* __restrict__ cv,
                           float* __restrict__ out_user) {
    int wave = (blockIdx.x * blockDim.x + threadIdx.x) >> 6;
    int lane = threadIdx.x & 63;
    if (wave >= N_USERS) return;
    int grp = lane >> 4;
    int t   = lane & 15;
    unsigned int s0 = u_row_start[wave];
    unsigned int s1 = u_row_start[wave + 1];
    const float4* itemsv = (const float4*)items;

    // ---- pass 1: weighted sum ----
    float4 um = make_float4(0.f, 0.f, 0.f, 0.f);
    for (unsigned int j = s0 + grp; j < s1; j += 4) {
        float v = cv[j];
        float4 g = itemsv[(size_t)ci[j] * 16 + t];
        um.x += v * g.x; um.y += v * g.y; um.z += v * g.z; um.w += v * g.w;
    }
    #pragma unroll
    for (int m = 16; m <= 32; m <<= 1) {
        um.x += __shfl_xor(um.x, m, 64);
        um.y += __shfl_xor(um.y, m, 64);
        um.z += __shfl_xor(um.z, m, 64);
        um.w += __shfl_xor(um.w, m, 64);
    }
    // fold +eps into the subtrahend: d = g - (um - eps)
    float4 umm = make_float4(um.x - 1e-6f, um.y - 1e-6f, um.z - 1e-6f, um.w - 1e-6f);

    // ---- pass 2: per-group online softmax ----
    float m_run = -1e30f, l = 0.0f;
    float4 acc = make_float4(0.f, 0.f, 0.f, 0.f);
    for (unsigned int j = s0 + grp; j < s1; j += 4) {
        float4 g = itemsv[(size_t)ci[j] * 16 + t];
        float dx = g.x - umm.x, dy = g.y - umm.y, dz = g.z - umm.z, dw = g.w - umm.w;
        float sq = dx * dx + dy * dy + dz * dz + dw * dw;
        #pragma unroll
        for (int m = 1; m <= 8; m <<= 1) sq += __shfl_xor(sq, m, 64);  // 16-lane group
        float sc = sqrtf(sq) * 5.0f;          // / TEMPERATURE (0.2)
        if (sc > m_run) {                      // no shfl inside: exec-mask safe
            float s = __expf(m_run - sc);      // first iter: exp(-1e30) -> 0
            l *= s;
            acc.x *= s; acc.y *= s; acc.z *= s; acc.w *= s;
            m_run = sc;
        }
        float e = __expf(sc - m_run);
        l += e;
        acc.x += e * g.x; acc.y += e * g.y; acc.z += e * g.z; acc.w += e * g.w;
    }

    // ---- merge the 4 group softmax states ----
    float M = fmaxf(m_run, __shfl_xor(m_run, 16, 64));
    M = fmaxf(M, __shfl_xor(M, 32, 64));
    float w = (l > 0.0f) ? __expf(m_run - M) : 0.0f;   // empty group contributes 0
    l *= w;
    acc.x *= w; acc.y *= w; acc.z *= w; acc.w *= w;
    #pragma unroll
    for (int m = 16; m <= 32; m <<= 1) {
        l     += __shfl_xor(l, m, 64);
        acc.x += __shfl_xor(acc.x, m, 64);
        acc.y += __shfl_xor(acc.y, m, 64);
        acc.z += __shfl_xor(acc.z, m, 64);
        acc.w += __shfl_xor(acc.w, m, 64);
    }
    float invl = (l > 0.0f) ? (1.0f / l) : 0.0f;       // empty user -> 0
    float4 ua = make_float4(acc.x * invl, acc.y * invl, acc.z * invl, acc.w * invl);

    // ---- epilogue: out_user += l2norm(ua) ----
    float sq2 = ua.x * ua.x + ua.y * ua.y + ua.z * ua.z + ua.w * ua.w;
    #pragma unroll
    for (int m = 1; m <= 8; m <<= 1) sq2 += __shfl_xor(sq2, m, 64);
    float inv = 1.0f / fmaxf(sqrtf(sq2), 1e-12f);
    if (grp == 0) {
        float4* op = (float4*)out_user + (size_t)wave * 16 + t;
        float4 c = *op;
        c.x += ua.x * inv; c.y += ua.y * inv; c.z += ua.z * inv; c.w += ua.w * inv;
        *op = c;
    }
}

extern "C" void kernel_launch(void* const* d_in, const int* in_sizes, int n_in,
                              void* d_out, int out_size, void* d_ws, size_t ws_size,
                              hipStream_t stream) {
    const float* user_emb   = (const float*)d_in[0];
    const float* entity_emb = (const float*)d_in[1];
    // d_in[2] = weight   (unused by reference)
    const int*   edge_index = (const int*)d_in[3];
    // d_in[4] = edge_type (unused by reference)
    const int*   iu = (const int*)d_in[5];
    const int*   ii = (const int*)d_in[6];
    const float* iv = (const float*)d_in[7];

    float* out_user = (float*)d_out;
    float* out_ent  = out_user + (size_t)N_USERS * CH;

    float* ws      = (float*)d_ws;
    float* ent_buf = ws;                               // N_ENT*CH
    float* summed  = ent_buf + (size_t)N_ENT * CH;     // N_ENT*CH
    // entity CSR
    unsigned int* cnt_u     = (unsigned int*)(summed + (size_t)N_ENT * CH); // N_ENT
    unsigned int* row_start = cnt_u + N_ENT;                                // N_ENT+1
    unsigned int* cursor    = row_start + (N_ENT + 1);                      // N_ENT+1
    unsigned int* partials  = cursor + (N_ENT + 1);                         // 256
    int*          col       = (int*)(partials + 256);                       // N_EDGES
    // user CSR
    unsigned int* ucnt        = (unsigned int*)(col + N_EDGES);             // N_USERS
    unsigned int* u_row_start = ucnt + N_USERS;                             // N_USERS+1
    unsigned int* ucursor     = u_row_start + (N_USERS + 1);                // N_USERS+1
    unsigned int* upartials   = ucursor + (N_USERS + 1);                    // 256
    int*          ci          = (int*)(upartials + 256);                    // NNZ
    float*        cv          = (float*)(ci + NNZ);                         // NNZ

    const int* head = edge_index;
    const int* tail = edge_index + N_EDGES;

    const int nScanE = (N_ENT   + ELEMS_PER_BLOCK - 1) / ELEMS_PER_BLOCK;   // 147
    const int nScanU = (N_USERS + ELEMS_PER_BLOCK - 1) / ELEMS_PER_BLOCK;   // 98

    // ---- entity CSR build (structure constant across hops) ----
    hipMemsetAsync(cnt_u, 0, (size_t)N_ENT * 4, stream);
    hist_k<<<(N_EDGES + 255) / 256, 256, 0, stream>>>(head, cnt_u, N_EDGES);
    scan1_k<<<nScanE, SCAN_BLOCK, 0, stream>>>(cnt_u, row_start, partials, N_ENT);
    scan2_k<<<1, SCAN_BLOCK, 0, stream>>>(partials, nScanE);
    addoff_k<<<nScanE, SCAN_BLOCK, 0, stream>>>(row_start, partials, N_ENT, N_EDGES);
    hipMemcpyAsync(cursor, row_start, (size_t)(N_ENT + 1) * 4, hipMemcpyDeviceToDevice, stream);
    scatter_ids_k<<<(N_EDGES + 255) / 256, 256, 0, stream>>>(head, tail, cursor, col);

    // ---- user CSR build ----
    hipMemsetAsync(ucnt, 0, (size_t)N_USERS * 4, stream);
    hist_k<<<(NNZ + 255) / 256, 256, 0, stream>>>(iu, ucnt, NNZ);
    scan1_k<<<nScanU, SCAN_BLOCK, 0, stream>>>(ucnt, u_row_start, upartials, N_USERS);
    scan2_k<<<1, SCAN_BLOCK, 0, stream>>>(upartials, nScanU);
    addoff_k<<<nScanU, SCAN_BLOCK, 0, stream>>>(u_row_start, upartials, N_USERS, NNZ);
    hipMemcpyAsync(ucursor, u_row_start, (size_t)(N_USERS + 1) * 4, hipMemcpyDeviceToDevice, stream);
    scatter_pairs_k<<<(NNZ + 255) / 256, 256, 0, stream>>>(iu, ii, iv, ucursor, ci, cv);

    // seed residuals
    hipMemcpyAsync(out_user, user_emb,   (size_t)N_USERS * CH * 4, hipMemcpyDeviceToDevice, stream);
    hipMemcpyAsync(out_ent,  entity_emb, (size_t)N_ENT   * CH * 4, hipMemcpyDeviceToDevice, stream);

    const float* ent_in = entity_emb;
    for (int hop = 0; hop < 2; ++hop) {
        gather_edges<<<((size_t)N_ENT * CH + 255) / 256, 256, 0, stream>>>(
            ent_in, row_start, col, summed);

        ent_finalize<<<((size_t)N_ENT * 16 + 255) / 256, 256, 0, stream>>>(
            summed, ent_buf, out_ent);

        // items == summed[:N_ITEMS*CH] (un-normalized entity_agg)
        fused_user<<<((size_t)N_USERS * CH + 255) / 256, 256, 0, stream>>>(
            summed, u_row_start, ci, cv, out_user);

        ent_in = ent_buf;
    }
}

// Round 6
// 653.220 us; speedup vs baseline: 3.9357x; 1.3366x over previous
//
#include <hip/hip_runtime.h>
#include <hip/hip_bf16.h>

#define N_USERS   100000
#define N_ITEMS   50000
#define N_ENT     150000
#define N_EDGES   2000000
#define NNZ       1000000
#define CH        64

#define CB_SHIFT  9
#define CB_SIZE   512
#define NB_E      ((N_ENT   + CB_SIZE - 1) >> CB_SHIFT)   // 293
#define NB_U      ((N_USERS + CB_SIZE - 1) >> CB_SHIFT)   // 196
#define A_CHUNK   4096

// ---------- A1: coarse histogram (LDS-staged) ----------
__global__ void coarse_count_k(const int* __restrict__ key, int n,
                               unsigned int* __restrict__ gcnt, int nb) {
    __shared__ unsigned int h[CB_SIZE];
    for (int i = threadIdx.x; i < nb; i += blockDim.x) h[i] = 0;
    __syncthreads();
    for (int e = blockIdx.x * blockDim.x + threadIdx.x; e < n; e += gridDim.x * blockDim.x)
        atomicAdd(&h[key[e] >> CB_SHIFT], 1u);
    __syncthreads();
    for (int i = threadIdx.x; i < nb; i += blockDim.x)
        if (h[i]) atomicAdd(&gcnt[i], h[i]);
}

// ---------- coarse exclusive scan (single block of 512 threads, nb<512) ----------
__global__ void coarse_scan_k(const unsigned int* __restrict__ gcnt,
                              unsigned int* __restrict__ base,
                              unsigned int* __restrict__ cursor, int nb) {
    __shared__ unsigned int s[512];
    int t = threadIdx.x;
    unsigned int v = (t < nb) ? gcnt[t] : 0u;
    s[t] = v;
    __syncthreads();
    for (int off = 1; off < 512; off <<= 1) {
        unsigned int u = 0;
        if (t >= off) u = s[t - off];
        __syncthreads();
        if (t >= off) s[t] += u;
        __syncthreads();
    }
    if (t < nb) {
        unsigned int excl = s[t] - v;
        base[t] = excl;
        cursor[t] = excl;
    }
    if (t == nb) base[t] = s[nb - 1];   // total
}

// ---------- A2 (entity): block-batched bin scatter of packed (local|tail) ----------
__global__ void binscat_ent_k(const int* __restrict__ head,
                              const int* __restrict__ tail,
                              unsigned int* __restrict__ cursor,
                              unsigned int* __restrict__ binned) {
    __shared__ unsigned int h[NB_E];
    __shared__ unsigned int bb[NB_E];
    int lo = blockIdx.x * A_CHUNK;
    int hi = min(lo + A_CHUNK, N_EDGES);
    for (int i = threadIdx.x; i < NB_E; i += blockDim.x) h[i] = 0;
    __syncthreads();
    for (int e = lo + threadIdx.x; e < hi; e += blockDim.x)
        atomicAdd(&h[head[e] >> CB_SHIFT], 1u);
    __syncthreads();
    for (int i = threadIdx.x; i < NB_E; i += blockDim.x) {
        unsigned int c = h[i];
        bb[i] = c ? atomicAdd(&cursor[i], c) : 0u;
        h[i] = 0;                       // reuse as running cursor
    }
    __syncthreads();
    for (int e = lo + threadIdx.x; e < hi; e += blockDim.x) {
        int hd = head[e];
        int b = hd >> CB_SHIFT;
        unsigned int r = atomicAdd(&h[b], 1u);
        unsigned int local = (unsigned int)hd & (CB_SIZE - 1);
        binned[bb[b] + r] = (local << 18) | (unsigned int)tail[e];   // tail < 2^18
    }
}

// ---------- A2 (user): packed (local|item) + val ----------
__global__ void binscat_user_k(const int* __restrict__ iu,
                               const int* __restrict__ ii,
                               const float* __restrict__ iv,
                               unsigned int* __restrict__ cursor,
                               unsigned int* __restrict__ binned,
                               float* __restrict__ binnedv) {
    __shared__ unsigned int h[NB_U];
    __shared__ unsigned int bb[NB_U];
    int lo = blockIdx.x * A_CHUNK;
    int hi = min(lo + A_CHUNK, NNZ);
    for (int i = threadIdx.x; i < NB_U; i += blockDim.x) h[i] = 0;
    __syncthreads();
    for (int e = lo + threadIdx.x; e < hi; e += blockDim.x)
        atomicAdd(&h[iu[e] >> CB_SHIFT], 1u);
    __syncthreads();
    for (int i = threadIdx.x; i < NB_U; i += blockDim.x) {
        unsigned int c = h[i];
        bb[i] = c ? atomicAdd(&cursor[i], c) : 0u;
        h[i] = 0;
    }
    __syncthreads();
    for (int e = lo + threadIdx.x; e < hi; e += blockDim.x) {
        int u = iu[e];
        int b = u >> CB_SHIFT;
        unsigned int r = atomicAdd(&h[b], 1u);
        unsigned int slot = bb[b] + r;
        unsigned int local = (unsigned int)u & (CB_SIZE - 1);
        binned[slot] = (local << 16) | (unsigned int)ii[e];          // item < 2^16
        binnedv[slot] = iv[e];
    }
}

// ---------- B (entity): per-bucket counting sort -> col + row_start ----------
__global__ void build_ent_k(const unsigned int* __restrict__ base,
                            const unsigned int* __restrict__ binned,
                            int* __restrict__ col,
                            unsigned int* __restrict__ row_start) {
    __shared__ unsigned int h[CB_SIZE];
    __shared__ unsigned int ex[CB_SIZE];
    __shared__ unsigned int pairs[256];
    int b = blockIdx.x;
    unsigned int s0 = base[b], s1 = base[b + 1];
    int t = threadIdx.x;
    h[2 * t] = 0; h[2 * t + 1] = 0;
    __syncthreads();
    for (unsigned int j = s0 + t; j < s1; j += 256)
        atomicAdd(&h[binned[j] >> 18], 1u);
    __syncthreads();
    unsigned int a0 = h[2 * t], a1 = h[2 * t + 1];
    pairs[t] = a0 + a1;
    __syncthreads();
    for (int off = 1; off < 256; off <<= 1) {
        unsigned int u = 0;
        if (t >= off) u = pairs[t - off];
        __syncthreads();
        if (t >= off) pairs[t] += u;
        __syncthreads();
    }
    unsigned int pe = pairs[t] - (a0 + a1);
    ex[2 * t] = pe;
    ex[2 * t + 1] = pe + a0;
    __syncthreads();
    int keybase = b << CB_SHIFT;
    #pragma unroll
    for (int k = 0; k < 2; ++k) {
        int i = 2 * t + k;
        int key = keybase + i;
        if (key < N_ENT) row_start[key] = s0 + ex[i];
    }
    if (b == 0 && t == 0) row_start[N_ENT] = base[NB_E];
    __syncthreads();
    h[2 * t] = 0; h[2 * t + 1] = 0;
    __syncthreads();
    for (unsigned int j = s0 + t; j < s1; j += 256) {
        unsigned int p = binned[j];
        unsigned int local = p >> 18;
        unsigned int r = atomicAdd(&h[local], 1u);
        col[s0 + ex[local] + r] = (int)(p & 0x3FFFFu);
    }
}

// ---------- B (user): per-bucket counting sort -> upair + u_row_start ----------
__global__ void build_user_k(const unsigned int* __restrict__ base,
                             const unsigned int* __restrict__ binned,
                             const float* __restrict__ binnedv,
                             int2* __restrict__ upair,
                             unsigned int* __restrict__ u_row_start) {
    __shared__ unsigned int h[CB_SIZE];
    __shared__ unsigned int ex[CB_SIZE];
    __shared__ unsigned int pairs[256];
    int b = blockIdx.x;
    unsigned int s0 = base[b], s1 = base[b + 1];
    int t = threadIdx.x;
    h[2 * t] = 0; h[2 * t + 1] = 0;
    __syncthreads();
    for (unsigned int j = s0 + t; j < s1; j += 256)
        atomicAdd(&h[binned[j] >> 16], 1u);
    __syncthreads();
    unsigned int a0 = h[2 * t], a1 = h[2 * t + 1];
    pairs[t] = a0 + a1;
    __syncthreads();
    for (int off = 1; off < 256; off <<= 1) {
        unsigned int u = 0;
        if (t >= off) u = pairs[t - off];
        __syncthreads();
        if (t >= off) pairs[t] += u;
        __syncthreads();
    }
    unsigned int pe = pairs[t] - (a0 + a1);
    ex[2 * t] = pe;
    ex[2 * t + 1] = pe + a0;
    __syncthreads();
    int keybase = b << CB_SHIFT;
    #pragma unroll
    for (int k = 0; k < 2; ++k) {
        int i = 2 * t + k;
        int key = keybase + i;
        if (key < N_USERS) u_row_start[key] = s0 + ex[i];
    }
    if (b == 0 && t == 0) u_row_start[N_USERS] = base[NB_U];
    __syncthreads();
    h[2 * t] = 0; h[2 * t + 1] = 0;
    __syncthreads();
    for (unsigned int j = s0 + t; j < s1; j += 256) {
        unsigned int p = binned[j];
        float v = binnedv[j];
        unsigned int local = p >> 16;
        unsigned int r = atomicAdd(&h[local], 1u);
        upair[s0 + ex[local] + r] = make_int2((int)(p & 0xFFFFu), __float_as_int(v));
    }
}

// ------------- CSR gather: one wave per entity row, 4x16-lane groups -------------
__global__ void gather_edges(const float* __restrict__ ent,
                             const unsigned int* __restrict__ row_start,
                             const int* __restrict__ col,
                             float* __restrict__ summed) {
    int wave = (blockIdx.x * blockDim.x + threadIdx.x) >> 6;
    int lane = threadIdx.x & 63;
    if (wave >= N_ENT) return;
    int grp = lane >> 4;
    int t   = lane & 15;
    unsigned int s0 = row_start[wave];
    unsigned int s1 = row_start[wave + 1];
    const float4* entv = (const float4*)ent;

    float4 acc = make_float4(0.f, 0.f, 0.f, 0.f);
    unsigned int j = s0 + grp;
    for (; j + 4 < s1; j += 8) {
        float4 a = entv[(size_t)col[j]     * 16 + t];
        float4 b = entv[(size_t)col[j + 4] * 16 + t];
        acc.x += a.x + b.x; acc.y += a.y + b.y;
        acc.z += a.z + b.z; acc.w += a.w + b.w;
    }
    if (j < s1) {
        float4 a = entv[(size_t)col[j] * 16 + t];
        acc.x += a.x; acc.y += a.y; acc.z += a.z; acc.w += a.w;
    }
    #pragma unroll
    for (int m = 16; m <= 32; m <<= 1) {
        acc.x += __shfl_xor(acc.x, m, 64);
        acc.y += __shfl_xor(acc.y, m, 64);
        acc.z += __shfl_xor(acc.z, m, 64);
        acc.w += __shfl_xor(acc.w, m, 64);
    }
    if (grp == 0) {
        float inv = 1.0f / fmaxf((float)(s1 - s0), 1.0f);
        ((float4*)summed)[(size_t)wave * 16 + t] =
            make_float4(acc.x * inv, acc.y * inv, acc.z * inv, acc.w * inv);
    }
}

// ------------- ent_next = l2norm(summed); out_ent = base + ent_next -------------
__global__ void ent_finalize(const float* __restrict__ summed,
                             float* __restrict__ ent_next,
                             const float* __restrict__ base_ent,
                             float* __restrict__ out_ent) {
    int idx = blockIdx.x * blockDim.x + threadIdx.x;
    int row = idx >> 4;
    int t = idx & 15;
    if (row >= N_ENT) return;
    size_t o = (size_t)row * 16 + t;
    float4 a = ((const float4*)summed)[o];
    float sq = a.x * a.x + a.y * a.y + a.z * a.z + a.w * a.w;
    #pragma unroll
    for (int m = 1; m <= 8; m <<= 1) sq += __shfl_xor(sq, m, 64);
    float inv = 1.0f / fmaxf(sqrtf(sq), 1e-12f);
    float4 v = make_float4(a.x * inv, a.y * inv, a.z * inv, a.w * inv);
    ((float4*)ent_next)[o] = v;
    float4 c = ((const float4*)base_ent)[o];
    c.x += v.x; c.y += v.y; c.z += v.z; c.w += v.w;
    ((float4*)out_ent)[o] = c;
}

// ------------- fused user pipeline: one wave per user, 4x16-lane groups -------------
__global__ void fused_user(const float* __restrict__ items,
                           const unsigned int* __restrict__ u_row_start,
                           const int2* __restrict__ up,
                           const float* __restrict__ base_user,
                           float* __restrict__ out_user) {
    int wave = (blockIdx.x * blockDim.x + threadIdx.x) >> 6;
    int lane = threadIdx.x & 63;
    if (wave >= N_USERS) return;
    int grp = lane >> 4;
    int t   = lane & 15;
    unsigned int s0 = u_row_start[wave];
    unsigned int s1 = u_row_start[wave + 1];
    const float4* itemsv = (const float4*)items;

    // ---- pass 1: weighted sum ----
    float4 um = make_float4(0.f, 0.f, 0.f, 0.f);
    for (unsigned int j = s0 + grp; j < s1; j += 4) {
        int2 p = up[j];
        float v = __int_as_float(p.y);
        float4 g = itemsv[(size_t)p.x * 16 + t];
        um.x += v * g.x; um.y += v * g.y; um.z += v * g.z; um.w += v * g.w;
    }
    #pragma unroll
    for (int m = 16; m <= 32; m <<= 1) {
        um.x += __shfl_xor(um.x, m, 64);
        um.y += __shfl_xor(um.y, m, 64);
        um.z += __shfl_xor(um.z, m, 64);
        um.w += __shfl_xor(um.w, m, 64);
    }
    float4 umm = make_float4(um.x - 1e-6f, um.y - 1e-6f, um.z - 1e-6f, um.w - 1e-6f);

    // ---- pass 2: per-group online softmax ----
    float m_run = -1e30f, l = 0.0f;
    float4 acc = make_float4(0.f, 0.f, 0.f, 0.f);
    for (unsigned int j = s0 + grp; j < s1; j += 4) {
        int2 p = up[j];
        float4 g = itemsv[(size_t)p.x * 16 + t];
        float dx = g.x - umm.x, dy = g.y - umm.y, dz = g.z - umm.z, dw = g.w - umm.w;
        float sq = dx * dx + dy * dy + dz * dz + dw * dw;
        #pragma unroll
        for (int m = 1; m <= 8; m <<= 1) sq += __shfl_xor(sq, m, 64);
        float sc = sqrtf(sq) * 5.0f;
        if (sc > m_run) {
            float s = __expf(m_run - sc);
            l *= s;
            acc.x *= s; acc.y *= s; acc.z *= s; acc.w *= s;
            m_run = sc;
        }
        float e = __expf(sc - m_run);
        l += e;
        acc.x += e * g.x; acc.y += e * g.y; acc.z += e * g.z; acc.w += e * g.w;
    }

    // ---- merge the 4 group softmax states ----
    float M = fmaxf(m_run, __shfl_xor(m_run, 16, 64));
    M = fmaxf(M, __shfl_xor(M, 32, 64));
    float w = (l > 0.0f) ? __expf(m_run - M) : 0.0f;
    l *= w;
    acc.x *= w; acc.y *= w; acc.z *= w; acc.w *= w;
    #pragma unroll
    for (int m = 16; m <= 32; m <<= 1) {
        l     += __shfl_xor(l, m, 64);
        acc.x += __shfl_xor(acc.x, m, 64);
        acc.y += __shfl_xor(acc.y, m, 64);
        acc.z += __shfl_xor(acc.z, m, 64);
        acc.w += __shfl_xor(acc.w, m, 64);
    }
    float invl = (l > 0.0f) ? (1.0f / l) : 0.0f;
    float4 ua = make_float4(acc.x * invl, acc.y * invl, acc.z * invl, acc.w * invl);

    float sq2 = ua.x * ua.x + ua.y * ua.y + ua.z * ua.z + ua.w * ua.w;
    #pragma unroll
    for (int m = 1; m <= 8; m <<= 1) sq2 += __shfl_xor(sq2, m, 64);
    float inv = 1.0f / fmaxf(sqrtf(sq2), 1e-12f);
    if (grp == 0) {
        size_t o = (size_t)wave * 16 + t;
        float4 c = ((const float4*)base_user)[o];
        c.x += ua.x * inv; c.y += ua.y * inv; c.z += ua.z * inv; c.w += ua.w * inv;
        ((float4*)out_user)[o] = c;
    }
}

extern "C" void kernel_launch(void* const* d_in, const int* in_sizes, int n_in,
                              void* d_out, int out_size, void* d_ws, size_t ws_size,
                              hipStream_t stream) {
    const float* user_emb   = (const float*)d_in[0];
    const float* entity_emb = (const float*)d_in[1];
    const int*   edge_index = (const int*)d_in[3];
    const int*   iu = (const int*)d_in[5];
    const int*   ii = (const int*)d_in[6];
    const float* iv = (const float*)d_in[7];

    float* out_user = (float*)d_out;
    float* out_ent  = out_user + (size_t)N_USERS * CH;

    float* ws      = (float*)d_ws;
    float* ent_buf = ws;                               // N_ENT*CH floats
    float* summed  = ent_buf + (size_t)N_ENT * CH;     // N_ENT*CH floats
    // build-time scratch ALIASED into summed (dead until gather_edges):
    unsigned int* binned_e  = (unsigned int*)summed;            // N_EDGES
    unsigned int* binned_u  = binned_e + N_EDGES;               // NNZ
    float*        binned_uv = (float*)(binned_u + NNZ);         // NNZ
    // persistent CSR after summed:
    unsigned int* row_start   = (unsigned int*)(summed + (size_t)N_ENT * CH); // N_ENT+1
    int*          col         = (int*)(row_start + N_ENT + 1);                // N_EDGES
    unsigned int* u_row_start = (unsigned int*)(col + N_EDGES);               // N_USERS+1
    int2*         upair       = (int2*)(u_row_start + N_USERS + 1);           // NNZ int2 (8B-aligned)
    unsigned int* cntE  = (unsigned int*)(upair + NNZ);                       // NB_E
    unsigned int* cntU  = cntE + NB_E;                                        // NB_U
    unsigned int* baseE = cntU + NB_U;                                        // NB_E+1
    unsigned int* curE  = baseE + NB_E + 1;                                   // NB_E
    unsigned int* baseU = curE + NB_E;                                        // NB_U+1
    unsigned int* curU  = baseU + NB_U + 1;                                   // NB_U

    const int* head = edge_index;
    const int* tail = edge_index + N_EDGES;

    // ---- CSR builds (structure constant across hops) ----
    hipMemsetAsync(cntE, 0, (size_t)(NB_E + NB_U) * 4, stream);   // cntE + cntU contiguous
    coarse_count_k<<<512, 256, 0, stream>>>(head, N_EDGES, cntE, NB_E);
    coarse_count_k<<<512, 256, 0, stream>>>(iu, NNZ, cntU, NB_U);
    coarse_scan_k<<<1, 512, 0, stream>>>(cntE, baseE, curE, NB_E);
    coarse_scan_k<<<1, 512, 0, stream>>>(cntU, baseU, curU, NB_U);
    binscat_ent_k<<<(N_EDGES + A_CHUNK - 1) / A_CHUNK, 256, 0, stream>>>(
        head, tail, curE, binned_e);
    binscat_user_k<<<(NNZ + A_CHUNK - 1) / A_CHUNK, 256, 0, stream>>>(
        iu, ii, iv, curU, binned_u, binned_uv);
    build_ent_k<<<NB_E, 256, 0, stream>>>(baseE, binned_e, col, row_start);
    build_user_k<<<NB_U, 256, 0, stream>>>(baseU, binned_u, binned_uv, upair, u_row_start);

    const float* ent_in = entity_emb;
    for (int hop = 0; hop < 2; ++hop) {
        gather_edges<<<((size_t)N_ENT * CH + 255) / 256, 256, 0, stream>>>(
            ent_in, row_start, col, summed);

        ent_finalize<<<((size_t)N_ENT * 16 + 255) / 256, 256, 0, stream>>>(
            summed, ent_buf, hop == 0 ? entity_emb : out_ent, out_ent);

        fused_user<<<((size_t)N_USERS * CH + 255) / 256, 256, 0, stream>>>(
            summed, u_row_start, upair, hop == 0 ? user_emb : out_user, out_user);

        ent_in = ent_buf;
    }
}

// Round 7
// 600.122 us; speedup vs baseline: 4.2839x; 1.0885x over previous
//
#include <hip/hip_runtime.h>
#include <hip/hip_bf16.h>

#define N_USERS   100000
#define N_ITEMS   50000
#define N_ENT     150000
#define N_EDGES   2000000
#define NNZ       1000000
#define CH        64

#define CB_SHIFT  9
#define CB_SIZE   512
#define NB_E      ((N_ENT   + CB_SIZE - 1) >> CB_SHIFT)   // 293
#define NB_U      ((N_USERS + CB_SIZE - 1) >> CB_SHIFT)   // 196
#define A_CHUNK   4096
#define UCACHE    32   // LDS-cached rows per user (P(deg>32 | lambda=10) ~ 3e-9; fallback reloads)

// ---- bf16 pack/unpack helpers (fp32 accumulate everywhere) ----
__device__ __forceinline__ float bflo(unsigned int u) { return __uint_as_float(u << 16); }
__device__ __forceinline__ float bfhi(unsigned int u) { return __uint_as_float(u & 0xffff0000u); }
__device__ __forceinline__ unsigned int pack_bf(float a, float b) {   // RNE
    unsigned int ua = __float_as_uint(a), ub = __float_as_uint(b);
    ua += 0x7fffu + ((ua >> 16) & 1u);
    ub += 0x7fffu + ((ub >> 16) & 1u);
    return (ua >> 16) | (ub & 0xffff0000u);
}

// ---------- A1: coarse histogram (LDS-staged) ----------
__global__ void coarse_count_k(const int* __restrict__ key, int n,
                               unsigned int* __restrict__ gcnt, int nb) {
    __shared__ unsigned int h[CB_SIZE];
    for (int i = threadIdx.x; i < nb; i += blockDim.x) h[i] = 0;
    __syncthreads();
    for (int e = blockIdx.x * blockDim.x + threadIdx.x; e < n; e += gridDim.x * blockDim.x)
        atomicAdd(&h[key[e] >> CB_SHIFT], 1u);
    __syncthreads();
    for (int i = threadIdx.x; i < nb; i += blockDim.x)
        if (h[i]) atomicAdd(&gcnt[i], h[i]);
}

// ---------- coarse exclusive scan (single block, nb < 512) ----------
__global__ void coarse_scan_k(const unsigned int* __restrict__ gcnt,
                              unsigned int* __restrict__ base,
                              unsigned int* __restrict__ cursor, int nb) {
    __shared__ unsigned int s[512];
    int t = threadIdx.x;
    unsigned int v = (t < nb) ? gcnt[t] : 0u;
    s[t] = v;
    __syncthreads();
    for (int off = 1; off < 512; off <<= 1) {
        unsigned int u = 0;
        if (t >= off) u = s[t - off];
        __syncthreads();
        if (t >= off) s[t] += u;
        __syncthreads();
    }
    if (t < nb) {
        unsigned int excl = s[t] - v;
        base[t] = excl;
        cursor[t] = excl;
    }
    if (t == nb) base[t] = s[nb - 1];   // total
}

// ---------- A2 (entity): block-batched bin scatter of packed (local|tail) ----------
__global__ void binscat_ent_k(const int* __restrict__ head,
                              const int* __restrict__ tail,
                              unsigned int* __restrict__ cursor,
                              unsigned int* __restrict__ binned) {
    __shared__ unsigned int h[NB_E];
    __shared__ unsigned int bb[NB_E];
    int lo = blockIdx.x * A_CHUNK;
    int hi = min(lo + A_CHUNK, N_EDGES);
    for (int i = threadIdx.x; i < NB_E; i += blockDim.x) h[i] = 0;
    __syncthreads();
    for (int e = lo + threadIdx.x; e < hi; e += blockDim.x)
        atomicAdd(&h[head[e] >> CB_SHIFT], 1u);
    __syncthreads();
    for (int i = threadIdx.x; i < NB_E; i += blockDim.x) {
        unsigned int c = h[i];
        bb[i] = c ? atomicAdd(&cursor[i], c) : 0u;
        h[i] = 0;
    }
    __syncthreads();
    for (int e = lo + threadIdx.x; e < hi; e += blockDim.x) {
        int hd = head[e];
        int b = hd >> CB_SHIFT;
        unsigned int r = atomicAdd(&h[b], 1u);
        unsigned int local = (unsigned int)hd & (CB_SIZE - 1);
        binned[bb[b] + r] = (local << 18) | (unsigned int)tail[e];   // tail < 2^18
    }
}

// ---------- A2 (user): packed (local|item) + val ----------
__global__ void binscat_user_k(const int* __restrict__ iu,
                               const int* __restrict__ ii,
                               const float* __restrict__ iv,
                               unsigned int* __restrict__ cursor,
                               unsigned int* __restrict__ binned,
                               float* __restrict__ binnedv) {
    __shared__ unsigned int h[NB_U];
    __shared__ unsigned int bb[NB_U];
    int lo = blockIdx.x * A_CHUNK;
    int hi = min(lo + A_CHUNK, NNZ);
    for (int i = threadIdx.x; i < NB_U; i += blockDim.x) h[i] = 0;
    __syncthreads();
    for (int e = lo + threadIdx.x; e < hi; e += blockDim.x)
        atomicAdd(&h[iu[e] >> CB_SHIFT], 1u);
    __syncthreads();
    for (int i = threadIdx.x; i < NB_U; i += blockDim.x) {
        unsigned int c = h[i];
        bb[i] = c ? atomicAdd(&cursor[i], c) : 0u;
        h[i] = 0;
    }
    __syncthreads();
    for (int e = lo + threadIdx.x; e < hi; e += blockDim.x) {
        int u = iu[e];
        int b = u >> CB_SHIFT;
        unsigned int r = atomicAdd(&h[b], 1u);
        unsigned int slot = bb[b] + r;
        unsigned int local = (unsigned int)u & (CB_SIZE - 1);
        binned[slot] = (local << 16) | (unsigned int)ii[e];          // item < 2^16
        binnedv[slot] = iv[e];
    }
}

// ---------- B (entity): per-bucket counting sort -> col + row_start ----------
__global__ void build_ent_k(const unsigned int* __restrict__ base,
                            const unsigned int* __restrict__ binned,
                            int* __restrict__ col,
                            unsigned int* __restrict__ row_start) {
    __shared__ unsigned int h[CB_SIZE];
    __shared__ unsigned int ex[CB_SIZE];
    __shared__ unsigned int pairs[256];
    int b = blockIdx.x;
    unsigned int s0 = base[b], s1 = base[b + 1];
    int t = threadIdx.x;
    h[2 * t] = 0; h[2 * t + 1] = 0;
    __syncthreads();
    for (unsigned int j = s0 + t; j < s1; j += 256)
        atomicAdd(&h[binned[j] >> 18], 1u);
    __syncthreads();
    unsigned int a0 = h[2 * t], a1 = h[2 * t + 1];
    pairs[t] = a0 + a1;
    __syncthreads();
    for (int off = 1; off < 256; off <<= 1) {
        unsigned int u = 0;
        if (t >= off) u = pairs[t - off];
        __syncthreads();
        if (t >= off) pairs[t] += u;
        __syncthreads();
    }
    unsigned int pe = pairs[t] - (a0 + a1);
    ex[2 * t] = pe;
    ex[2 * t + 1] = pe + a0;
    __syncthreads();
    int keybase = b << CB_SHIFT;
    #pragma unroll
    for (int k = 0; k < 2; ++k) {
        int i = 2 * t + k;
        int key = keybase + i;
        if (key < N_ENT) row_start[key] = s0 + ex[i];
    }
    if (b == 0 && t == 0) row_start[N_ENT] = base[NB_E];
    __syncthreads();
    h[2 * t] = 0; h[2 * t + 1] = 0;
    __syncthreads();
    for (unsigned int j = s0 + t; j < s1; j += 256) {
        unsigned int p = binned[j];
        unsigned int local = p >> 18;
        unsigned int r = atomicAdd(&h[local], 1u);
        col[s0 + ex[local] + r] = (int)(p & 0x3FFFFu);
    }
}

// ---------- B (user): per-bucket counting sort -> upair + u_row_start ----------
__global__ void build_user_k(const unsigned int* __restrict__ base,
                             const unsigned int* __restrict__ binned,
                             const float* __restrict__ binnedv,
                             int2* __restrict__ upair,
                             unsigned int* __restrict__ u_row_start) {
    __shared__ unsigned int h[CB_SIZE];
    __shared__ unsigned int ex[CB_SIZE];
    __shared__ unsigned int pairs[256];
    int b = blockIdx.x;
    unsigned int s0 = base[b], s1 = base[b + 1];
    int t = threadIdx.x;
    h[2 * t] = 0; h[2 * t + 1] = 0;
    __syncthreads();
    for (unsigned int j = s0 + t; j < s1; j += 256)
        atomicAdd(&h[binned[j] >> 16], 1u);
    __syncthreads();
    unsigned int a0 = h[2 * t], a1 = h[2 * t + 1];
    pairs[t] = a0 + a1;
    __syncthreads();
    for (int off = 1; off < 256; off <<= 1) {
        unsigned int u = 0;
        if (t >= off) u = pairs[t - off];
        __syncthreads();
        if (t >= off) pairs[t] += u;
        __syncthreads();
    }
    unsigned int pe = pairs[t] - (a0 + a1);
    ex[2 * t] = pe;
    ex[2 * t + 1] = pe + a0;
    __syncthreads();
    int keybase = b << CB_SHIFT;
    #pragma unroll
    for (int k = 0; k < 2; ++k) {
        int i = 2 * t + k;
        int key = keybase + i;
        if (key < N_USERS) u_row_start[key] = s0 + ex[i];
    }
    if (b == 0 && t == 0) u_row_start[N_USERS] = base[NB_U];
    __syncthreads();
    h[2 * t] = 0; h[2 * t + 1] = 0;
    __syncthreads();
    for (unsigned int j = s0 + t; j < s1; j += 256) {
        unsigned int p = binned[j];
        float v = binnedv[j];
        unsigned int local = p >> 16;
        unsigned int r = atomicAdd(&h[local], 1u);
        upair[s0 + ex[local] + r] = make_int2((int)(p & 0xFFFFu), __float_as_int(v));
    }
}

// ---------- convert entity_emb fp32 -> bf16 (one thread per uint2 = 4 ch) ----------
__global__ void convert_k(const float* __restrict__ src, uint2* __restrict__ dst) {
    int i = blockIdx.x * blockDim.x + threadIdx.x;
    if (i >= N_ENT * 16) return;
    float4 a = ((const float4*)src)[i];
    dst[i] = make_uint2(pack_bf(a.x, a.y), pack_bf(a.z, a.w));
}

// ------------- CSR gather (bf16 in, fp32 acc): one wave per entity row -------------
__global__ void gather_edges(const uint2* __restrict__ entb,
                             const unsigned int* __restrict__ row_start,
                             const int* __restrict__ col,
                             float* __restrict__ summed) {
    int wave = (blockIdx.x * blockDim.x + threadIdx.x) >> 6;
    int lane = threadIdx.x & 63;
    if (wave >= N_ENT) return;
    int grp = lane >> 4;
    int t   = lane & 15;
    unsigned int s0 = row_start[wave];
    unsigned int s1 = row_start[wave + 1];

    float4 acc = make_float4(0.f, 0.f, 0.f, 0.f);
    unsigned int j = s0 + grp;
    for (; j + 4 < s1; j += 8) {
        uint2 a = entb[(size_t)col[j]     * 16 + t];
        uint2 b = entb[(size_t)col[j + 4] * 16 + t];
        acc.x += bflo(a.x) + bflo(b.x); acc.y += bfhi(a.x) + bfhi(b.x);
        acc.z += bflo(a.y) + bflo(b.y); acc.w += bfhi(a.y) + bfhi(b.y);
    }
    if (j < s1) {
        uint2 a = entb[(size_t)col[j] * 16 + t];
        acc.x += bflo(a.x); acc.y += bfhi(a.x);
        acc.z += bflo(a.y); acc.w += bfhi(a.y);
    }
    #pragma unroll
    for (int m = 16; m <= 32; m <<= 1) {
        acc.x += __shfl_xor(acc.x, m, 64);
        acc.y += __shfl_xor(acc.y, m, 64);
        acc.z += __shfl_xor(acc.z, m, 64);
        acc.w += __shfl_xor(acc.w, m, 64);
    }
    if (grp == 0) {
        float inv = 1.0f / fmaxf((float)(s1 - s0), 1.0f);
        ((float4*)summed)[(size_t)wave * 16 + t] =
            make_float4(acc.x * inv, acc.y * inv, acc.z * inv, acc.w * inv);
    }
}

// ------------- finalize: ent_bf16 <- bf16(l2norm(summed)); out_ent = base + l2norm;
//               items_bf16 <- bf16(summed) for item rows -------------
__global__ void ent_finalize(const float* __restrict__ summed,
                             uint2* __restrict__ ent_bf16,
                             uint2* __restrict__ items_bf16,
                             const float* __restrict__ base_ent,
                             float* __restrict__ out_ent) {
    int idx = blockIdx.x * blockDim.x + threadIdx.x;
    int row = idx >> 4;
    int t = idx & 15;
    if (row >= N_ENT) return;
    size_t o = (size_t)row * 16 + t;
    float4 a = ((const float4*)summed)[o];
    if (row < N_ITEMS)
        items_bf16[o] = make_uint2(pack_bf(a.x, a.y), pack_bf(a.z, a.w));
    float sq = a.x * a.x + a.y * a.y + a.z * a.z + a.w * a.w;
    #pragma unroll
    for (int m = 1; m <= 8; m <<= 1) sq += __shfl_xor(sq, m, 64);
    float inv = 1.0f / fmaxf(sqrtf(sq), 1e-12f);
    float4 v = make_float4(a.x * inv, a.y * inv, a.z * inv, a.w * inv);
    ent_bf16[o] = make_uint2(pack_bf(v.x, v.y), pack_bf(v.z, v.w));
    float4 c = ((const float4*)base_ent)[o];
    c.x += v.x; c.y += v.y; c.z += v.z; c.w += v.w;
    ((float4*)out_ent)[o] = c;
}

// ------------- fused user pipeline: one wave per user, 4x16-lane groups -------------
// pass 1 gathers each row ONCE (bf16), caching raw rows in LDS; pass 2 reads LDS.
__global__ void fused_user(const uint2* __restrict__ itemsb,
                           const unsigned int* __restrict__ u_row_start,
                           const int2* __restrict__ up,
                           const float* __restrict__ base_user,
                           float* __restrict__ out_user) {
    __shared__ uint2 cache[4][UCACHE][16];   // 16 KB per block
    int wave = (blockIdx.x * blockDim.x + threadIdx.x) >> 6;
    int w    = threadIdx.x >> 6;             // wave in block
    int lane = threadIdx.x & 63;
    if (wave >= N_USERS) return;
    int grp = lane >> 4;
    int t   = lane & 15;
    unsigned int s0 = u_row_start[wave];
    unsigned int s1 = u_row_start[wave + 1];

    // ---- pass 1: gather once, cache, weighted sum ----
    float4 um = make_float4(0.f, 0.f, 0.f, 0.f);
    for (unsigned int j = s0 + grp; j < s1; j += 4) {
        int2 p = up[j];
        uint2 r = itemsb[(size_t)p.x * 16 + t];
        int slot = (int)(j - s0);
        if (slot < UCACHE) cache[w][slot][t] = r;
        float v = __int_as_float(p.y);
        um.x += v * bflo(r.x); um.y += v * bfhi(r.x);
        um.z += v * bflo(r.y); um.w += v * bfhi(r.y);
    }
    #pragma unroll
    for (int m = 16; m <= 32; m <<= 1) {
        um.x += __shfl_xor(um.x, m, 64);
        um.y += __shfl_xor(um.y, m, 64);
        um.z += __shfl_xor(um.z, m, 64);
        um.w += __shfl_xor(um.w, m, 64);
    }
    float4 umm = make_float4(um.x - 1e-6f, um.y - 1e-6f, um.z - 1e-6f, um.w - 1e-6f);

    // ---- pass 2: per-group online softmax from LDS (same-wave RAW, no barrier) ----
    float m_run = -1e30f, l = 0.0f;
    float4 acc = make_float4(0.f, 0.f, 0.f, 0.f);
    for (unsigned int j = s0 + grp; j < s1; j += 4) {
        int slot = (int)(j - s0);
        uint2 r = (slot < UCACHE) ? cache[w][slot][t]
                                  : itemsb[(size_t)up[j].x * 16 + t];
        float gx = bflo(r.x), gy = bfhi(r.x), gz = bflo(r.y), gw = bfhi(r.y);
        float dx = gx - umm.x, dy = gy - umm.y, dz = gz - umm.z, dw = gw - umm.w;
        float sq = dx * dx + dy * dy + dz * dz + dw * dw;
        #pragma unroll
        for (int m = 1; m <= 8; m <<= 1) sq += __shfl_xor(sq, m, 64);
        float sc = sqrtf(sq) * 5.0f;          // / TEMPERATURE (0.2)
        if (sc > m_run) {                      // no shfl inside: exec-mask safe
            float s = __expf(m_run - sc);
            l *= s;
            acc.x *= s; acc.y *= s; acc.z *= s; acc.w *= s;
            m_run = sc;
        }
        float e = __expf(sc - m_run);
        l += e;
        acc.x += e * gx; acc.y += e * gy; acc.z += e * gz; acc.w += e * gw;
    }

    // ---- merge the 4 group softmax states ----
    float M = fmaxf(m_run, __shfl_xor(m_run, 16, 64));
    M = fmaxf(M, __shfl_xor(M, 32, 64));
    float wgt = (l > 0.0f) ? __expf(m_run - M) : 0.0f;
    l *= wgt;
    acc.x *= wgt; acc.y *= wgt; acc.z *= wgt; acc.w *= wgt;
    #pragma unroll
    for (int m = 16; m <= 32; m <<= 1) {
        l     += __shfl_xor(l, m, 64);
        acc.x += __shfl_xor(acc.x, m, 64);
        acc.y += __shfl_xor(acc.y, m, 64);
        acc.z += __shfl_xor(acc.z, m, 64);
        acc.w += __shfl_xor(acc.w, m, 64);
    }
    float invl = (l > 0.0f) ? (1.0f / l) : 0.0f;
    float4 ua = make_float4(acc.x * invl, acc.y * invl, acc.z * invl, acc.w * invl);

    float sq2 = ua.x * ua.x + ua.y * ua.y + ua.z * ua.z + ua.w * ua.w;
    #pragma unroll
    for (int m = 1; m <= 8; m <<= 1) sq2 += __shfl_xor(sq2, m, 64);
    float inv = 1.0f / fmaxf(sqrtf(sq2), 1e-12f);
    if (grp == 0) {
        size_t o = (size_t)wave * 16 + t;
        float4 c = ((const float4*)base_user)[o];
        c.x += ua.x * inv; c.y += ua.y * inv; c.z += ua.z * inv; c.w += ua.w * inv;
        ((float4*)out_user)[o] = c;
    }
}

extern "C" void kernel_launch(void* const* d_in, const int* in_sizes, int n_in,
                              void* d_out, int out_size, void* d_ws, size_t ws_size,
                              hipStream_t stream) {
    const float* user_emb   = (const float*)d_in[0];
    const float* entity_emb = (const float*)d_in[1];
    const int*   edge_index = (const int*)d_in[3];
    const int*   iu = (const int*)d_in[5];
    const int*   ii = (const int*)d_in[6];
    const float* iv = (const float*)d_in[7];

    float* out_user = (float*)d_out;
    float* out_ent  = out_user + (size_t)N_USERS * CH;

    float* ws     = (float*)d_ws;
    float* summed = ws;                                 // N_ENT*CH fp32 (38.4 MB)
    // build-time scratch ALIASED into summed (dead until gather_edges):
    unsigned int* binned_e  = (unsigned int*)summed;             // N_EDGES
    unsigned int* binned_u  = binned_e + N_EDGES;                // NNZ
    float*        binned_uv = (float*)(binned_u + NNZ);          // NNZ
    // persistent buffers after summed (all 8-byte aligned in order):
    uint2* ent_bf16   = (uint2*)(summed + (size_t)N_ENT * CH);   // N_ENT*16
    uint2* items_bf16 = ent_bf16 + (size_t)N_ENT * 16;           // N_ITEMS*16
    int2*  upair      = (int2*)(items_bf16 + (size_t)N_ITEMS * 16);  // NNZ
    unsigned int* row_start   = (unsigned int*)(upair + NNZ);    // N_ENT+1
    int*          col         = (int*)(row_start + N_ENT + 1);   // N_EDGES
    unsigned int* u_row_start = (unsigned int*)(col + N_EDGES);  // N_USERS+1
    unsigned int* cntE  = u_row_start + N_USERS + 1;             // NB_E
    unsigned int* cntU  = cntE + NB_E;                           // NB_U
    unsigned int* baseE = cntU + NB_U;                           // NB_E+1
    unsigned int* curE  = baseE + NB_E + 1;                      // NB_E
    unsigned int* baseU = curE + NB_E;                           // NB_U+1
    unsigned int* curU  = baseU + NB_U + 1;                      // NB_U

    const int* head = edge_index;
    const int* tail = edge_index + N_EDGES;

    // ---- CSR builds (structure constant across hops) ----
    hipMemsetAsync(cntE, 0, (size_t)(NB_E + NB_U) * 4, stream);
    coarse_count_k<<<512, 256, 0, stream>>>(head, N_EDGES, cntE, NB_E);
    coarse_count_k<<<512, 256, 0, stream>>>(iu, NNZ, cntU, NB_U);
    coarse_scan_k<<<1, 512, 0, stream>>>(cntE, baseE, curE, NB_E);
    coarse_scan_k<<<1, 512, 0, stream>>>(cntU, baseU, curU, NB_U);
    binscat_ent_k<<<(N_EDGES + A_CHUNK - 1) / A_CHUNK, 256, 0, stream>>>(
        head, tail, curE, binned_e);
    binscat_user_k<<<(NNZ + A_CHUNK - 1) / A_CHUNK, 256, 0, stream>>>(
        iu, ii, iv, curU, binned_u, binned_uv);
    build_ent_k<<<NB_E, 256, 0, stream>>>(baseE, binned_e, col, row_start);
    build_user_k<<<NB_U, 256, 0, stream>>>(baseU, binned_u, binned_uv, upair, u_row_start);

    // seed bf16 entity table for hop 0
    convert_k<<<(N_ENT * 16 + 255) / 256, 256, 0, stream>>>(entity_emb, ent_bf16);

    for (int hop = 0; hop < 2; ++hop) {
        gather_edges<<<((size_t)N_ENT * CH + 255) / 256, 256, 0, stream>>>(
            ent_bf16, row_start, col, summed);

        ent_finalize<<<((size_t)N_ENT * 16 + 255) / 256, 256, 0, stream>>>(
            summed, ent_bf16, items_bf16, hop == 0 ? entity_emb : out_ent, out_ent);

        fused_user<<<((size_t)N_USERS * CH + 255) / 256, 256, 0, stream>>>(
            items_bf16, u_row_start, upair, hop == 0 ? user_emb : out_user, out_user);
    }
}